// Round 5
// baseline (218.699 us; speedup 1.0000x reference)
//
#include <hip/hip_runtime.h>
#include <math.h>

#define L_IN     262144
#define N_FRAME  1024
#define AMIN     1e-10f
#define DRANGE   80.0f
#define UNITS_CH 2080            // (64 frames * 256 hop + 256)/8 16B-units per channel
#define WS_HI_OFF   4096
#define WS_HALF     524288       // 16 frags * 32 kk * 64 lanes * 16B
#define N4_OUT   ((32 * 257 * 1024 * 2) / 4)   // float4 count of the real output

typedef short bf16x8 __attribute__((ext_vector_type(8)));
typedef short bf16x4 __attribute__((ext_vector_type(4)));
typedef float f32x16 __attribute__((ext_vector_type(16)));

__device__ __forceinline__ short f2bf(float f) {           // fp32 -> bf16 RNE
    unsigned u = __float_as_uint(f);
    u = (u + 0x7FFFu + ((u >> 16) & 1u)) >> 16;
    return (short)u;
}
__device__ __forceinline__ float bf2f(short h) {
    return __uint_as_float(((unsigned)(unsigned short)h) << 16);
}
__device__ __forceinline__ int swz(int u) { return u ^ ((u >> 5) & 7); }

// W -> bf16 hi/lo in 32x32x16 MFMA B-frag order.  (unchanged)
__global__ __launch_bounds__(256) void wconv_kernel(
    const float* __restrict__ kr, const float* __restrict__ ki,
    short* __restrict__ whi, short* __restrict__ wlo, unsigned* __restrict__ wsmax)
{
    if (blockIdx.x == 0 && threadIdx.x == 0) wsmax[0] = 0u;
    const int tid  = threadIdx.x;
    const int pair = blockIdx.x * 4 + (tid >> 6);   // (fi,kk) in [0,512)
    const int lane = tid & 63;
    const int fi = pair >> 5, kk = pair & 31;
    const int g = fi >> 1, nf = fi & 1;
    const int n  = lane & 31;
    const int k0 = kk * 16 + (lane >> 5) * 8;
    const int f  = g * 32 + n;
    bf16x8 h8, l8;
    #pragma unroll
    for (int j = 0; j < 8; ++j) {
        const int k = k0 + j;
        float w;
        if (nf == 1 && g == 0 && n == 0) w = kr[k * 257 + 256];   // Nyquist column
        else                             w = (nf ? ki : kr)[k * 257 + f];
        short hh = f2bf(w);
        h8[j] = hh;
        l8[j] = f2bf(w - bf2f(hh));
    }
    const int off = ((fi * 32 + kk) * 64 + lane) * 8;
    *(bf16x8*)(whi + off) = h8;
    *(bf16x8*)(wlo + off) = l8;
}

// One block: 64 frames x 2 channels (M=128) x all 257 filters; 8 waves, wave = filter group.
// K-loop: round-3 plain form (NO manual pipelining — round 4 proved the compiler's own
// scheduling is better: manual dbuf/rotate cost -26%).  T5: setprio(1) around the 24-MFMA
// cluster — barrier-free loop means waves drift, so the CU scheduler has role diversity
// to arbitrate.  (512,2): NO higher min-waves (round-1 spill), bl JIT (pass-3 distance).
__global__ __launch_bounds__(512, 2) void spec_kernel(
    const float* __restrict__ x,
    const short* __restrict__ whi, const short* __restrict__ wlo,
    float* __restrict__ out, unsigned* __restrict__ wsmax)
{
    // A hi/lo buffers; reused after the K-loop as the fp32 output-transpose buffer S.
    __shared__ __align__(16) char smem[2 * 2 * UNITS_CH * 8 * sizeof(short)]; // 133120 B
    __shared__ float wmax[8];
    short* Ah = (short*)smem;                                   // 66560 B
    short* Al = (short*)(smem + 2 * UNITS_CH * 8 * sizeof(short));
    float* S  = (float*)smem;                                   // [128][257] = 131584 B

    const int blk = blockIdx.x;
    const int tt  = blk & 15;
    const int b   = blk >> 4;
    const int tid = threadIdx.x;
    const int lane = tid & 63;
    const int g    = tid >> 6;          // wave = filter group
    const int col  = lane & 31;
    const int half = lane >> 5;

    // ---- stage A: prefetch-all-then-convert; 130 chunks of 256 samples ----
    const int s_origin = tt * 16384 - 128;
    float4 pv[17];
    #pragma unroll
    for (int it = 0; it < 17; ++it) {
        const int cc = g + it * 8;
        if (cc < 130) {
            const int ch   = (cc >= 65) ? 1 : 0;
            const int c    = cc - ch * 65;
            const int base = s_origin + c * 256;
            const float* xp = x + ((size_t)b * 2 + ch) * L_IN;
            const int i4 = base + lane * 4;
            if (base >= 0 && base + 256 <= L_IN) {
                pv[it] = *(const float4*)(xp + i4);
            } else {                       // only (tt==0,c==0) and (tt==15,c==64)
                float4 t;
                t.x = (i4     >= 0 && i4     < L_IN) ? xp[i4]     : 0.0f;
                t.y = (i4 + 1 >= 0 && i4 + 1 < L_IN) ? xp[i4 + 1] : 0.0f;
                t.z = (i4 + 2 >= 0 && i4 + 2 < L_IN) ? xp[i4 + 2] : 0.0f;
                t.w = (i4 + 3 >= 0 && i4 + 3 < L_IN) ? xp[i4 + 3] : 0.0f;
                pv[it] = t;
            }
        }
    }
    #pragma unroll
    for (int it = 0; it < 17; ++it) {
        const int cc = g + it * 8;
        if (cc < 130) {
            const int ch = (cc >= 65) ? 1 : 0;
            const int c  = cc - ch * 65;
            float v[4];
            v[0] = pv[it].x; v[1] = pv[it].y; v[2] = pv[it].z; v[3] = pv[it].w;
            bf16x4 h4, l4;
            #pragma unroll
            for (int j = 0; j < 4; ++j) {
                short hh = f2bf(v[j]);
                h4[j] = hh;
                l4[j] = f2bf(v[j] - bf2f(hh));
            }
            const int u = c * 32 + (lane >> 1);
            const int e = (ch * UNITS_CH + swz(u)) * 8 + (lane & 1) * 4;
            *(bf16x4*)&Ah[e] = h4;     // ds_write_b64
            *(bf16x4*)&Al[e] = l4;
        }
    }
    __syncthreads();

    // ---- K loop: barrier-free; bh reg-dbuf'd, bl loaded per-kp (pass-3 use) ----
    f32x16 acc[2][2][2];               // [s(frame-half)][mf(channel)][nf(cos/sin)]
    #pragma unroll
    for (int s = 0; s < 2; ++s)
        #pragma unroll
        for (int mf = 0; mf < 2; ++mf)
            #pragma unroll
            for (int nf = 0; nf < 2; ++nf)
                #pragma unroll
                for (int r = 0; r < 16; ++r) acc[s][mf][nf][r] = 0.0f;

    const int laneoff = lane * 8;
    bf16x8 bh[2][2];
    #pragma unroll
    for (int nf = 0; nf < 2; ++nf)
        #pragma unroll
        for (int kh = 0; kh < 2; ++kh)
            bh[nf][kh] = *(const bf16x8*)(whi + (((g * 2 + nf) * 32 + kh) * 64) * 8 + laneoff);

    for (int kp = 0; kp < 16; ++kp) {
        bf16x8 nbh[2][2], bl[2][2];
        #pragma unroll
        for (int s = 0; s < 2; ++s) {
            bf16x8 ah[2][2], al[2][2];
            #pragma unroll
            for (int mf = 0; mf < 2; ++mf)
                #pragma unroll
                for (int kh = 0; kh < 2; ++kh) {
                    const int u = s * 1024 + col * 32 + kp * 4 + kh * 2 + half;
                    const int e = (mf * UNITS_CH + swz(u)) * 8;
                    ah[mf][kh] = *(const bf16x8*)&Ah[e];
                    al[mf][kh] = *(const bf16x8*)&Al[e];
                }
            if (s == 0) {
                #pragma unroll
                for (int nf = 0; nf < 2; ++nf)
                    #pragma unroll
                    for (int kh = 0; kh < 2; ++kh)
                        bl[nf][kh] = *(const bf16x8*)(wlo + (((g * 2 + nf) * 32 + kp * 2 + kh) * 64) * 8 + laneoff);
                if (kp < 15) {
                    #pragma unroll
                    for (int nf = 0; nf < 2; ++nf)
                        #pragma unroll
                        for (int kh = 0; kh < 2; ++kh)
                            nbh[nf][kh] = *(const bf16x8*)(whi + (((g * 2 + nf) * 32 + (kp + 1) * 2 + kh) * 64) * 8 + laneoff);
                }
            }
            // T5: prefer this wave while its 24-MFMA cluster issues
            __builtin_amdgcn_s_setprio(1);
            // pass-major: hh, lh, hl — same-acc dependents 4 apart
            #pragma unroll
            for (int kh = 0; kh < 2; ++kh)
                #pragma unroll
                for (int mf = 0; mf < 2; ++mf)
                    #pragma unroll
                    for (int nf = 0; nf < 2; ++nf)
                        acc[s][mf][nf] = __builtin_amdgcn_mfma_f32_32x32x16_bf16(ah[mf][kh], bh[nf][kh], acc[s][mf][nf], 0, 0, 0);
            #pragma unroll
            for (int kh = 0; kh < 2; ++kh)
                #pragma unroll
                for (int mf = 0; mf < 2; ++mf)
                    #pragma unroll
                    for (int nf = 0; nf < 2; ++nf)
                        acc[s][mf][nf] = __builtin_amdgcn_mfma_f32_32x32x16_bf16(al[mf][kh], bh[nf][kh], acc[s][mf][nf], 0, 0, 0);
            #pragma unroll
            for (int kh = 0; kh < 2; ++kh)
                #pragma unroll
                for (int mf = 0; mf < 2; ++mf)
                    #pragma unroll
                    for (int nf = 0; nf < 2; ++nf)
                        acc[s][mf][nf] = __builtin_amdgcn_mfma_f32_32x32x16_bf16(ah[mf][kh], bl[nf][kh], acc[s][mf][nf], 0, 0, 0);
            __builtin_amdgcn_s_setprio(0);
        }
        if (kp < 15) {
            #pragma unroll
            for (int nf = 0; nf < 2; ++nf)
                #pragma unroll
                for (int kh = 0; kh < 2; ++kh)
                    bh[nf][kh] = nbh[nf][kh];
        }
    }

    // ---- epilogue: p = re^2+im^2 -> LDS transpose S[128][257] -> coalesced stores ----
    // C/D layout (32x32): n = lane&31, m = (r&3) + 8*(r>>2) + 4*(lane>>5)
    __syncthreads();                       // all A-reads done; reuse LDS as S
    const bool nyq = (g == 0) && (col == 0);
    float pmax = 0.0f;
    #pragma unroll
    for (int s = 0; s < 2; ++s)
        #pragma unroll
        for (int mf = 0; mf < 2; ++mf) {   // mf = channel
            #pragma unroll
            for (int r = 0; r < 16; ++r) {
                const int m   = (r & 3) + 8 * (r >> 2) + 4 * half;
                const int row = (s * 32 + m) * 2 + mf;
                const float re = acc[s][mf][0][r];
                const float im = acc[s][mf][1][r];
                const float imq = nyq ? 0.0f : im;
                float p = fmaxf(re * re + imq * imq, AMIN);
                pmax = fmaxf(pmax, p);
                S[row * 257 + g * 32 + col] = p;   // bank (row+col)%32: conflict-free
                if (nyq) {                 // sin-frag col0 carries f=256 re
                    float pn = fmaxf(im * im, AMIN);
                    pmax = fmaxf(pmax, pn);
                    S[row * 257 + 256] = pn;
                }
            }
        }
    #pragma unroll
    for (int off = 32; off > 0; off >>= 1)
        pmax = fmaxf(pmax, __shfl_down(pmax, off, 64));
    if (lane == 0) wmax[g] = pmax;
    __syncthreads();                       // guards both wmax and S
    if (tid == 0) {
        float m2 = wmax[0];
        #pragma unroll
        for (int w = 1; w < 8; ++w) m2 = fmaxf(m2, wmax[w]);
        atomicMax(wsmax, __float_as_uint(m2));
    }
    // out float offset = b*526336 + f*2048 + (tt*64 + tl)*2 + ch; S row = tl*2+ch.
    float* obase = out + (size_t)b * 526336 + (size_t)tt * 128;
    for (int q = tid; q < 257 * 128; q += 512) {
        const int f = q >> 7, tl2 = q & 127;
        obase[(size_t)f * 2048 + tl2] = S[tl2 * 257 + f];
    }
}

__global__ __launch_bounds__(256) void finalize_kernel(
    float* __restrict__ out, const unsigned* __restrict__ ws_max, int n4)
{
    const int i = blockIdx.x * 256 + threadIdx.x;
    if (i >= n4) return;
    const float mlog = 10.0f * log10f(__uint_as_float(*ws_max));
    float4 p = ((const float4*)out)[i];
    float4 v;
    v.x = fmaxf(10.0f * log10f(p.x) - mlog, -DRANGE);
    v.y = fmaxf(10.0f * log10f(p.y) - mlog, -DRANGE);
    v.z = fmaxf(10.0f * log10f(p.z) - mlog, -DRANGE);
    v.w = fmaxf(10.0f * log10f(p.w) - mlog, -DRANGE);
    ((float4*)out)[i] = v;
}

extern "C" void kernel_launch(void* const* d_in, const int* in_sizes, int n_in,
                              void* d_out, int out_size, void* d_ws, size_t ws_size,
                              hipStream_t stream) {
    const float* x  = (const float*)d_in[0];
    const float* kr = (const float*)d_in[1];
    const float* ki = (const float*)d_in[2];
    float* out      = (float*)d_out;

    unsigned* wsmax = (unsigned*)d_ws;
    short* whi      = (short*)((char*)d_ws + WS_HI_OFF);
    short* wlo      = (short*)((char*)d_ws + WS_HI_OFF + WS_HALF);

    wconv_kernel<<<128, 256, 0, stream>>>(kr, ki, whi, wlo, wsmax);

    const int nblocks = 32 * 16;       // b * t-tiles (64 frames per tile)
    spec_kernel<<<nblocks, 512, 0, stream>>>(x, whi, wlo, out, wsmax);

    const int n4 = N4_OUT;
    finalize_kernel<<<(n4 + 255) / 256, 256, 0, stream>>>(out, wsmax, n4);
}

// Round 6
// 214.623 us; speedup vs baseline: 1.0190x; 1.0190x over previous
//
#include <hip/hip_runtime.h>
#include <math.h>

#define L_IN     262144
#define N_FRAME  1024
#define AMIN     1e-10f
#define DRANGE   80.0f
#define UNITS_CH 1056            // (32 frames * 256 hop + 256)/8 16B-units per channel
#define WS_HI_OFF   4096
#define WS_HALF     524288       // 16 frags * 32 kk * 64 lanes * 16B
#define N4_OUT   ((32 * 257 * 1024 * 2) / 4)   // float4 count of the real output

typedef short bf16x8 __attribute__((ext_vector_type(8)));
typedef short bf16x4 __attribute__((ext_vector_type(4)));
typedef float f32x16 __attribute__((ext_vector_type(16)));

__device__ __forceinline__ short f2bf(float f) {           // fp32 -> bf16 RNE
    unsigned u = __float_as_uint(f);
    u = (u + 0x7FFFu + ((u >> 16) & 1u)) >> 16;
    return (short)u;
}
__device__ __forceinline__ float bf2f(short h) {
    return __uint_as_float(((unsigned)(unsigned short)h) << 16);
}
__device__ __forceinline__ int swz(int u) { return u ^ ((u >> 5) & 7); }

// W -> bf16 hi/lo in 32x32x16 MFMA B-frag order.  (unchanged)
__global__ __launch_bounds__(256) void wconv_kernel(
    const float* __restrict__ kr, const float* __restrict__ ki,
    short* __restrict__ whi, short* __restrict__ wlo, unsigned* __restrict__ wsmax)
{
    if (blockIdx.x == 0 && threadIdx.x == 0) wsmax[0] = 0u;
    const int tid  = threadIdx.x;
    const int pair = blockIdx.x * 4 + (tid >> 6);   // (fi,kk) in [0,512)
    const int lane = tid & 63;
    const int fi = pair >> 5, kk = pair & 31;
    const int g = fi >> 1, nf = fi & 1;
    const int n  = lane & 31;
    const int k0 = kk * 16 + (lane >> 5) * 8;
    const int f  = g * 32 + n;
    bf16x8 h8, l8;
    #pragma unroll
    for (int j = 0; j < 8; ++j) {
        const int k = k0 + j;
        float w;
        if (nf == 1 && g == 0 && n == 0) w = kr[k * 257 + 256];   // Nyquist column
        else                             w = (nf ? ki : kr)[k * 257 + f];
        short hh = f2bf(w);
        h8[j] = hh;
        l8[j] = f2bf(w - bf2f(hh));
    }
    const int off = ((fi * 32 + kk) * 64 + lane) * 8;
    *(bf16x8*)(whi + off) = h8;
    *(bf16x8*)(wlo + off) = l8;
}

// One block: 32 frames x 2 channels (M=64) x all 257 filters; 8 waves, wave = filter group.
// OCCUPANCY BUILD: total regs <= 128 (64 AGPR acc + <=64 VGPR) -> 16 waves/CU =
// 4 waves/SIMD, 2 blocks/CU co-resident (LDS 2x68KB <= 160KB).  kh-serial K-loop with
// JIT B loads (no dbuf) keeps VGPR pressure low; 4-way TLP hides L2/LDS latency.
// (512,4) here is safe (unlike round-1's M=128: need ~240 vs cap 128 -> spill disaster);
// genuine need is ~110-125.
__global__ __launch_bounds__(512, 4) void spec_kernel(
    const float* __restrict__ x,
    const short* __restrict__ whi, const short* __restrict__ wlo,
    float* __restrict__ out, unsigned* __restrict__ wsmax)
{
    // A hi/lo buffers; reused after the K-loop as the fp32 output-transpose buffer S.
    __shared__ __align__(16) char smem[2 * 2 * UNITS_CH * 8 * sizeof(short)]; // 67584 B
    __shared__ float wmax[8];
    short* Ah = (short*)smem;                                   // 33792 B
    short* Al = (short*)(smem + 2 * UNITS_CH * 8 * sizeof(short));
    float* S  = (float*)smem;                                   // [64][257] = 65792 B

    const int blk = blockIdx.x;
    const int tt  = blk & 31;
    const int b   = blk >> 5;
    const int tid = threadIdx.x;
    const int lane = tid & 63;
    const int g    = tid >> 6;          // wave = filter group
    const int col  = lane & 31;
    const int half = lane >> 5;

    // ---- stage A: rolled; wave-contiguous 256-sample chunks, lane i float4 @ +16B*i ----
    const int s_origin = tt * 8192 - 128;
    for (int cc = g; cc < 66; cc += 8) {
        const int ch   = (cc >= 33) ? 1 : 0;
        const int c    = cc - ch * 33;
        const int base = s_origin + c * 256;
        const float* xp = x + ((size_t)b * 2 + ch) * L_IN;
        const int i4 = base + lane * 4;
        float v[4];
        if (base >= 0 && base + 256 <= L_IN) {
            float4 p = *(const float4*)(xp + i4);
            v[0] = p.x; v[1] = p.y; v[2] = p.z; v[3] = p.w;
        } else {
            #pragma unroll
            for (int j = 0; j < 4; ++j) {
                const int idx = i4 + j;
                v[j] = (idx >= 0 && idx < L_IN) ? xp[idx] : 0.0f;
            }
        }
        bf16x4 h4, l4;
        #pragma unroll
        for (int j = 0; j < 4; ++j) {
            short hh = f2bf(v[j]);
            h4[j] = hh;
            l4[j] = f2bf(v[j] - bf2f(hh));
        }
        const int u = c * 32 + (lane >> 1);
        const int e = (ch * UNITS_CH + swz(u)) * 8 + (lane & 1) * 4;
        *(bf16x4*)&Ah[e] = h4;     // ds_write_b64
        *(bf16x4*)&Al[e] = l4;
    }
    __syncthreads();

    // ---- K loop: barrier-free, kh-serial, JIT loads (register diet) ----
    f32x16 acc[2][2];                  // [mf(channel)][nf(cos/sin)]
    #pragma unroll
    for (int mf = 0; mf < 2; ++mf)
        #pragma unroll
        for (int nf = 0; nf < 2; ++nf)
            #pragma unroll
            for (int r = 0; r < 16; ++r) acc[mf][nf][r] = 0.0f;

    const int laneoff = lane * 8;
    const short* whiW = whi + (g * 2) * 32 * 64 * 8 + laneoff;   // nf stride = 32*64*8
    const short* wloW = wlo + (g * 2) * 32 * 64 * 8 + laneoff;

    for (int kk = 0; kk < 32; ++kk) {
        const int u0 = col * 32 + kk * 2 + half;
        const int e0 = swz(u0) * 8;
        const int e1 = (UNITS_CH + swz(u0)) * 8;
        const int wo = kk * 64 * 8;
        // hh
        bf16x8 bh0 = *(const bf16x8*)(whiW + wo);
        bf16x8 bh1 = *(const bf16x8*)(whiW + 32 * 64 * 8 + wo);
        bf16x8 ah0 = *(const bf16x8*)&Ah[e0];
        bf16x8 ah1 = *(const bf16x8*)&Ah[e1];
        acc[0][0] = __builtin_amdgcn_mfma_f32_32x32x16_bf16(ah0, bh0, acc[0][0], 0, 0, 0);
        acc[0][1] = __builtin_amdgcn_mfma_f32_32x32x16_bf16(ah0, bh1, acc[0][1], 0, 0, 0);
        acc[1][0] = __builtin_amdgcn_mfma_f32_32x32x16_bf16(ah1, bh0, acc[1][0], 0, 0, 0);
        acc[1][1] = __builtin_amdgcn_mfma_f32_32x32x16_bf16(ah1, bh1, acc[1][1], 0, 0, 0);
        // hl
        bf16x8 bl0 = *(const bf16x8*)(wloW + wo);
        bf16x8 bl1 = *(const bf16x8*)(wloW + 32 * 64 * 8 + wo);
        acc[0][0] = __builtin_amdgcn_mfma_f32_32x32x16_bf16(ah0, bl0, acc[0][0], 0, 0, 0);
        acc[0][1] = __builtin_amdgcn_mfma_f32_32x32x16_bf16(ah0, bl1, acc[0][1], 0, 0, 0);
        acc[1][0] = __builtin_amdgcn_mfma_f32_32x32x16_bf16(ah1, bl0, acc[1][0], 0, 0, 0);
        acc[1][1] = __builtin_amdgcn_mfma_f32_32x32x16_bf16(ah1, bl1, acc[1][1], 0, 0, 0);
        // lh
        bf16x8 al0 = *(const bf16x8*)&Al[e0];
        bf16x8 al1 = *(const bf16x8*)&Al[e1];
        acc[0][0] = __builtin_amdgcn_mfma_f32_32x32x16_bf16(al0, bh0, acc[0][0], 0, 0, 0);
        acc[0][1] = __builtin_amdgcn_mfma_f32_32x32x16_bf16(al0, bh1, acc[0][1], 0, 0, 0);
        acc[1][0] = __builtin_amdgcn_mfma_f32_32x32x16_bf16(al1, bh0, acc[1][0], 0, 0, 0);
        acc[1][1] = __builtin_amdgcn_mfma_f32_32x32x16_bf16(al1, bh1, acc[1][1], 0, 0, 0);
    }

    // ---- epilogue: p = re^2+im^2 -> LDS transpose S[64][257] -> coalesced stores ----
    // C/D layout (32x32): n = lane&31, m = (r&3) + 8*(r>>2) + 4*(lane>>5)
    __syncthreads();                       // all A-reads done; reuse LDS as S
    const bool nyq = (g == 0) && (col == 0);
    float pmax = 0.0f;
    #pragma unroll
    for (int mf = 0; mf < 2; ++mf) {       // mf = channel
        #pragma unroll
        for (int r = 0; r < 16; ++r) {
            const int m   = (r & 3) + 8 * (r >> 2) + 4 * half;
            const int row = m * 2 + mf;
            const float re = acc[mf][0][r];
            const float im = acc[mf][1][r];
            const float imq = nyq ? 0.0f : im;
            float p = fmaxf(re * re + imq * imq, AMIN);
            pmax = fmaxf(pmax, p);
            S[row * 257 + g * 32 + col] = p;   // bank (row+col)%32: conflict-free
            if (nyq) {                     // sin-frag col0 carries f=256 re
                float pn = fmaxf(im * im, AMIN);
                pmax = fmaxf(pmax, pn);
                S[row * 257 + 256] = pn;
            }
        }
    }
    #pragma unroll
    for (int off = 32; off > 0; off >>= 1)
        pmax = fmaxf(pmax, __shfl_down(pmax, off, 64));
    if (lane == 0) wmax[g] = pmax;
    __syncthreads();                       // guards both wmax and S
    if (tid == 0) {
        float m2 = wmax[0];
        #pragma unroll
        for (int w = 1; w < 8; ++w) m2 = fmaxf(m2, wmax[w]);
        atomicMax(wsmax, __float_as_uint(m2));
    }
    // per f: 64 consecutive floats (t local 0..31 x mf) = 16 float4; 4112 float4 total
    float* obase = out + (size_t)b * 526336 + (size_t)tt * 64;
    for (int q = tid; q < 257 * 16; q += 512) {
        const int f = q >> 4, part = q & 15;
        float4 vv;
        vv.x = S[(part * 4 + 0) * 257 + f];
        vv.y = S[(part * 4 + 1) * 257 + f];
        vv.z = S[(part * 4 + 2) * 257 + f];
        vv.w = S[(part * 4 + 3) * 257 + f];
        *(float4*)(obase + (size_t)f * 2048 + part * 4) = vv;
    }
}

__global__ __launch_bounds__(256) void finalize_kernel(
    float* __restrict__ out, const unsigned* __restrict__ ws_max, int n4)
{
    const int i = blockIdx.x * 256 + threadIdx.x;
    if (i >= n4) return;
    const float mlog = 10.0f * log10f(__uint_as_float(*ws_max));
    float4 p = ((const float4*)out)[i];
    float4 v;
    v.x = fmaxf(10.0f * log10f(p.x) - mlog, -DRANGE);
    v.y = fmaxf(10.0f * log10f(p.y) - mlog, -DRANGE);
    v.z = fmaxf(10.0f * log10f(p.z) - mlog, -DRANGE);
    v.w = fmaxf(10.0f * log10f(p.w) - mlog, -DRANGE);
    ((float4*)out)[i] = v;
}

extern "C" void kernel_launch(void* const* d_in, const int* in_sizes, int n_in,
                              void* d_out, int out_size, void* d_ws, size_t ws_size,
                              hipStream_t stream) {
    const float* x  = (const float*)d_in[0];
    const float* kr = (const float*)d_in[1];
    const float* ki = (const float*)d_in[2];
    float* out      = (float*)d_out;

    unsigned* wsmax = (unsigned*)d_ws;
    short* whi      = (short*)((char*)d_ws + WS_HI_OFF);
    short* wlo      = (short*)((char*)d_ws + WS_HI_OFF + WS_HALF);

    wconv_kernel<<<128, 256, 0, stream>>>(kr, ki, whi, wlo, wsmax);

    const int nblocks = 32 * 32;       // b * t-tiles (32 frames per tile)
    spec_kernel<<<nblocks, 512, 0, stream>>>(x, whi, wlo, out, wsmax);

    const int n4 = N4_OUT;
    finalize_kernel<<<(n4 + 255) / 256, 256, 0, stream>>>(out, wsmax, n4);
}